// Round 25
// baseline (52.852 us; speedup 1.0000x reference)
//
#include <hip/hip_runtime.h>

#define N2 (768 * 768)
#define NH 32
#define PPB 64       // pairs per block; 9216 blocks
#define TPB 256      // 4 threads per pair, 4 waves
#define CAP 1792     // staged LDS entries (multiple of 256); global fallback beyond

typedef float v4f __attribute__((ext_vector_type(4)));

// ---------- Pass 1: parallel block-boundary search ----------
// key(e) = (coeff==0 ? INT_MAX : pair[e]) is globally sorted (pair_idx sorted
// ascending over valid prefix, padding coeff==0 at the tail). bnd[j] =
// lower_bound(key, j*PPB). 9217 independent searches, fully parallel.
__global__ void bounds_kernel(const int* __restrict__ pair,
                              const float* __restrict__ coeff,
                              int* __restrict__ bnd, int M) {
    int j = blockIdx.x * blockDim.x + threadIdx.x;
    if (j > N2 / PPB) return;
    int target = j * PPB;
    int lo = 0, hi = M;
    while (lo < hi) {
        int mid = (lo + hi) >> 1;
        int key = (coeff[mid] == 0.f) ? 0x7fffffff : pair[mid];
        if (key < target) lo = mid + 1; else hi = mid;
    }
    bnd[j] = lo;
}

// async global->LDS, 16B per lane: LDS dst = wave-uniform base + lane*16,
// global src = per-lane address. Tracked by vmcnt.
#define GLOAD_LDS16(GP, LP)                                                   \
    __builtin_amdgcn_global_load_lds(                                        \
        (const __attribute__((address_space(1))) void*)(GP),                 \
        (__attribute__((address_space(3))) void*)(LP), 16, 0, 0)

// ---------- Pass 2: DMA-staged fused stage + walk + expand ----------
// out[h,p] = b[h]*S0[p] + sum_k W[h][k]*S[k][p] over pair p's entry segment.
// Staging: 3 global_load_lds (16B/lane, 1KB/wave-instr) per 256-entry chunk,
// issued before anything else -> fire-and-forget DMA, no VGPR round-trip,
// maximal outstanding stream. vmcnt(0)+barrier, then boundary detection from
// pairL in LDS (window starts/ends are run boundaries by construction of
// bnd[], so no out-of-window neighbor reads needed). Walk: 4 thr/pair, 2
// adjacent entries/iter (stride 8) from nodeL/coeffL, ea gathers L1-hot.
// 2-step shfl_xor merge; sums to LDS; expansion = 2 v4f NT stores/thread.
// Every output element written exactly once; missing pairs keep ps=pe=0 ->
// exact zeros, matching segment_sum.
__global__ __launch_bounds__(256) void fused_kernel(
    const int* __restrict__ pair, const int* __restrict__ node,
    const float* __restrict__ coeff, const float* __restrict__ ea,
    const float* __restrict__ W, const float* __restrict__ bias,
    const int* __restrict__ bnd, float* __restrict__ out, int M)
{
    __shared__ int   pairL[CAP];         // 7 KB
    __shared__ int   nodeL[CAP];         // 7 KB
    __shared__ float coeffL[CAP];        // 7 KB
    __shared__ float sum[5][PPB];        // 1.25 KB
    __shared__ int ps[PPB], pe[PPB];
    __shared__ float sW[NH * 4];
    __shared__ float sBias[NH];

    const int t = threadIdx.x;
    const int lane = t & 63, w = t >> 6;
    const int p0 = blockIdx.x * PPB;

    const int s0 = bnd[blockIdx.x], s1 = bnd[blockIdx.x + 1];
    const int s0a = s0 & ~3;             // 4-aligned (16B-aligned) staging base
    const int cntA = s1 - s0a;           // staged span
    const bool staged = (cntA <= CAP);   // block-uniform

    // ---- issue DMA staging FIRST (maximize time-in-flight) ----
    if (staged) {
        for (int cb = w * 256; cb < cntA; cb += 1024) {   // wave w's 256-entry chunks
            const int g0 = s0a + cb;
            if (g0 + 256 <= M) {
                const int off = lane << 2;               // 4 entries per lane
                GLOAD_LDS16(pair  + g0 + off, &pairL[cb]);
                GLOAD_LDS16(node  + g0 + off, &nodeL[cb]);
                GLOAD_LDS16(coeff + g0 + off, &coeffL[cb]);
            } else {
                // rare tail chunk at end of arrays: masked VGPR copy
                for (int j = lane; j < 256; j += 64) {
                    const int e = g0 + j;
                    if (e < M) {
                        pairL[cb + j]  = pair[e];
                        nodeL[cb + j]  = node[e];
                        coeffL[cb + j] = coeff[e];
                    }
                }
            }
        }
    }

    if (t < NH * 4) sW[t] = W[t];
    if (t < NH) sBias[t] = bias[t];
    if (t < PPB) { ps[t] = 0; pe[t] = 0; }
    asm volatile("s_waitcnt vmcnt(0)" ::: "memory");   // DMA complete (this wave)
    __syncthreads();                                   // all waves' staging visible

    if (staged) {
        // boundary detection from LDS; window edges are run boundaries by
        // construction (entries before s0 / after s1-1 belong to other pair
        // ranges), so no out-of-window reads.
        const int i0 = s0 - s0a;
        for (int i = i0 + t; i < cntA; i += TPB) {
            const int pp = pairL[i];
            if (i == i0 || pairL[i - 1] != pp) ps[pp - p0] = i;
            if (i == cntA - 1 || pairL[i + 1] != pp) pe[pp - p0] = i + 1;
        }
    } else {
        const int cnt = s1 - s0;
        for (int i = t; i < cnt; i += TPB) {
            int e = s0 + i;
            int pp = pair[e];
            if (i == 0 || pair[e - 1] != pp) ps[pp - p0] = e;      // global idx
            if (i == cnt - 1 || pair[e + 1] != pp) pe[pp - p0] = e + 1;
        }
    }
    __syncthreads();

    // 4 threads/pair, 2 adjacent entries per iteration (stride 8)
    const int q = t >> 2, sub = t & 3;
    float a0 = 0.f, a1 = 0.f, a2 = 0.f, a3 = 0.f, a4 = 0.f;
    float b0s = 0.f, b1s = 0.f, b2s = 0.f, b3s = 0.f, b4s = 0.f;
    {
        const int e = pe[q];
        int k = ps[q] + (sub << 1);
        if (staged) {
            for (; k < e; k += 8) {
                const float ccA = coeffL[k];
                const int   nA  = nodeL[k];
                const float4 vA = *reinterpret_cast<const float4*>(ea + nA * 4);
                a0 += ccA; a1 += ccA * vA.x; a2 += ccA * vA.y; a3 += ccA * vA.z; a4 += ccA * vA.w;
                if (k + 1 < e) {
                    const float ccB = coeffL[k + 1];
                    const int   nB  = nodeL[k + 1];
                    const float4 vB = *reinterpret_cast<const float4*>(ea + nB * 4);
                    b0s += ccB; b1s += ccB * vB.x; b2s += ccB * vB.y; b3s += ccB * vB.z; b4s += ccB * vB.w;
                }
            }
        } else {
            for (; k < e; k += 8) {
                const float ccA = coeff[k];
                const float4 vA = *reinterpret_cast<const float4*>(ea + node[k] * 4);
                a0 += ccA; a1 += ccA * vA.x; a2 += ccA * vA.y; a3 += ccA * vA.z; a4 += ccA * vA.w;
                if (k + 1 < e) {
                    const float ccB = coeff[k + 1];
                    const float4 vB = *reinterpret_cast<const float4*>(ea + node[k + 1] * 4);
                    b0s += ccB; b1s += ccB * vB.x; b2s += ccB * vB.y; b3s += ccB * vB.z; b4s += ccB * vB.w;
                }
            }
        }
    }
    a0 += b0s; a1 += b1s; a2 += b2s; a3 += b3s; a4 += b4s;
#pragma unroll
    for (int d = 1; d < 4; d <<= 1) {
        a0 += __shfl_xor(a0, d); a1 += __shfl_xor(a1, d); a2 += __shfl_xor(a2, d);
        a3 += __shfl_xor(a3, d); a4 += __shfl_xor(a4, d);
    }
    if (sub == 0) {
        sum[0][q] = a0; sum[1][q] = a1; sum[2][q] = a2;
        sum[3][q] = a3; sum[4][q] = a4;
    }
    __syncthreads();

    // expansion: wave w2, lane l; group g = l&15 -> pairs 4g..4g+3;
    // channels h = w2*8 + (l>>4)*2 + j, j in {0,1}.
    {
        const int l = t & 63, w2 = t >> 6;
        const int g = l & 15, quad = l >> 4;
        const v4f c0 = *reinterpret_cast<const v4f*>(&sum[0][4 * g]);
        const v4f c1 = *reinterpret_cast<const v4f*>(&sum[1][4 * g]);
        const v4f c2 = *reinterpret_cast<const v4f*>(&sum[2][4 * g]);
        const v4f c3 = *reinterpret_cast<const v4f*>(&sum[3][4 * g]);
        const v4f c4 = *reinterpret_cast<const v4f*>(&sum[4][4 * g]);
        const size_t op = (size_t)p0 + 4 * g;
#pragma unroll
        for (int j = 0; j < 2; ++j) {
            const int h = w2 * 8 + quad * 2 + j;
            const float bb = sBias[h], w0 = sW[h * 4], w1 = sW[h * 4 + 1],
                        wz = sW[h * 4 + 2], w3 = sW[h * 4 + 3];
            v4f o = bb * c0 + w0 * c1 + w1 * c2 + wz * c3 + w3 * c4;
            __builtin_nontemporal_store(o, reinterpret_cast<v4f*>(out + (size_t)h * N2 + op));
        }
    }
}

extern "C" void kernel_launch(void* const* d_in, const int* in_sizes, int n_in,
                              void* d_out, int out_size, void* d_ws, size_t ws_size,
                              hipStream_t stream) {
    // inputs: 0=x 1=edge_attr 2=W 3=b 4=edge_idx 5=pair_idx 6=node_idx 7=coeff 8=num_nodes
    const float* ea    = (const float*)d_in[1];
    const float* W     = (const float*)d_in[2];
    const float* b     = (const float*)d_in[3];
    const int*   pair  = (const int*)d_in[5];
    const int*   node  = (const int*)d_in[6];
    const float* coeff = (const float*)d_in[7];
    float* out = (float*)d_out;
    int M = in_sizes[5];

    int* bnd = (int*)d_ws;   // N2/PPB + 1 = 9217 ints

    bounds_kernel<<<(N2 / PPB + 1 + 255) / 256, 256, 0, stream>>>(pair, coeff, bnd, M);

    fused_kernel<<<N2 / PPB, TPB, 0, stream>>>(pair, node, coeff, ea, W, b, bnd, out, M);
}

// Round 26
// 48.189 us; speedup vs baseline: 1.0968x; 1.0968x over previous
//
#include <hip/hip_runtime.h>

#define N2 (768 * 768)
#define NH 32
#define PPB 64       // pairs per block; 9216 blocks
#define TPB 256      // 4 threads per pair, 4 waves
#define CAP 1664     // staged LDS slots (13.3 KB); global-walk fallback beyond

typedef float v4f __attribute__((ext_vector_type(4)));

// ---------- Pass 1: parallel block-boundary search ----------
// key(e) = (coeff==0 ? INT_MAX : pair[e]) is globally sorted (pair_idx sorted
// ascending over valid prefix, padding coeff==0 at the tail). bnd[j] =
// lower_bound(key, j*PPB). 9217 independent searches, fully parallel.
__global__ void bounds_kernel(const int* __restrict__ pair,
                              const float* __restrict__ coeff,
                              int* __restrict__ bnd, int M) {
    int j = blockIdx.x * blockDim.x + threadIdx.x;
    if (j > N2 / PPB) return;
    int target = j * PPB;
    int lo = 0, hi = M;
    while (lo < hi) {
        int mid = (lo + hi) >> 1;
        int key = (coeff[mid] == 0.f) ? 0x7fffffff : pair[mid];
        if (key < target) lo = mid + 1; else hi = mid;
    }
    bnd[j] = lo;
}

// ---------- Pass 2: fused stage + walk + expand (champion structure) ----------
// out[h,p] = b[h]*S0[p] + sum_k W[h][k]*S[k][p] over pair p's entry segment.
// Vectorized stage (int4/int4/float4, 16B/lane; window aligned to 4; M%4==0
// keeps loads in-bounds), run boundaries from registers (2 scalar L1-hit
// neighbor loads), two ds_write_b128 per 4 entries. 4 threads/pair walk
// 2 adjacent entries per iteration (stride 8) from LDS -> half the dependent
// iterations, 2 independent gathers in flight (ea 12KB L1-hot). 2-step
// shfl_xor merge, sums to dedicated LDS buffer, expansion = 2 v4f NT stores
// per thread. Every output element written exactly once; missing pairs keep
// ps=pe=0 -> exact zeros, matching segment_sum.
__global__ __launch_bounds__(256) void fused_kernel(
    const int* __restrict__ pair, const int* __restrict__ node,
    const float* __restrict__ coeff, const float* __restrict__ ea,
    const float* __restrict__ W, const float* __restrict__ bias,
    const int* __restrict__ bnd, float* __restrict__ out, int M)
{
    __shared__ float2 ent[CAP];          // 13.3 KB
    __shared__ float sum[5][PPB];        // 1.25 KB
    __shared__ int ps[PPB], pe[PPB];
    __shared__ float sW[NH * 4];
    __shared__ float sBias[NH];

    const int t = threadIdx.x;
    const int p0 = blockIdx.x * PPB;

    if (t < NH * 4) sW[t] = W[t];
    if (t < NH) sBias[t] = bias[t];
    if (t < PPB) { ps[t] = 0; pe[t] = 0; }
    __syncthreads();

    const int s0 = bnd[blockIdx.x], s1 = bnd[blockIdx.x + 1];
    const int s0a = s0 & ~3;             // 4-aligned staging base
    const int cntA = s1 - s0a;           // staged span
    const bool staged = (cntA <= CAP);   // block-uniform

    if (staged) {
        for (int i4 = t; (i4 << 2) < cntA; i4 += TPB) {
            const int e0 = s0a + (i4 << 2);
            const int4   p4 = reinterpret_cast<const int4*>(pair)[e0 >> 2];
            const int4   n4 = reinterpret_cast<const int4*>(node)[e0 >> 2];
            const float4 c4 = reinterpret_cast<const float4*>(coeff)[e0 >> 2];
            v4f w0; w0.x = c4.x; w0.y = __int_as_float(n4.x);
                    w0.z = c4.y; w0.w = __int_as_float(n4.y);
            v4f w1; w1.x = c4.z; w1.y = __int_as_float(n4.z);
                    w1.z = c4.w; w1.w = __int_as_float(n4.w);
            *reinterpret_cast<v4f*>(&ent[i4 << 2])       = w0;
            *reinterpret_cast<v4f*>(&ent[(i4 << 2) + 2]) = w1;
            const int prevp = (e0 > 0) ? pair[e0 - 1] : -1;
            const int nextp = (e0 + 4 < M) ? pair[e0 + 4] : -1;
            const int pk[6] = { prevp, p4.x, p4.y, p4.z, p4.w, nextp };
#pragma unroll
            for (int j = 0; j < 4; ++j) {
                const int e = e0 + j;
                const int pp = pk[j + 1];
                if (e >= s0 && e < s1) {
                    if (e == s0 || pk[j] != pp) ps[pp - p0] = e;
                    if (e == s1 - 1 || pk[j + 2] != pp) pe[pp - p0] = e + 1;
                }
            }
        }
    } else {
        const int cnt = s1 - s0;
        for (int i = t; i < cnt; i += TPB) {
            int e = s0 + i;
            int pp = pair[e];
            if (i == 0 || pair[e - 1] != pp) ps[pp - p0] = e;
            if (i == cnt - 1 || pair[e + 1] != pp) pe[pp - p0] = e + 1;
        }
    }
    __syncthreads();

    // 4 threads/pair, 2 adjacent entries per iteration (stride 8):
    // q = t>>2, sub = t&3 -> entries s+2sub, s+2sub+1, s+2sub+8, ...
    const int q = t >> 2, sub = t & 3;
    float a0 = 0.f, a1 = 0.f, a2 = 0.f, a3 = 0.f, a4 = 0.f;
    float b0s = 0.f, b1s = 0.f, b2s = 0.f, b3s = 0.f, b4s = 0.f;
    {
        const int e = pe[q];
        int k = ps[q] + (sub << 1);
        if (staged) {
            for (; k < e; k += 8) {
                const float2 enA = ent[k - s0a];
                const float ccA = enA.x;
                const int ndA = __float_as_int(enA.y);
                const float4 vA = *reinterpret_cast<const float4*>(ea + ndA * 4);
                a0 += ccA; a1 += ccA * vA.x; a2 += ccA * vA.y; a3 += ccA * vA.z; a4 += ccA * vA.w;
                if (k + 1 < e) {
                    const float2 enB = ent[k + 1 - s0a];
                    const float ccB = enB.x;
                    const int ndB = __float_as_int(enB.y);
                    const float4 vB = *reinterpret_cast<const float4*>(ea + ndB * 4);
                    b0s += ccB; b1s += ccB * vB.x; b2s += ccB * vB.y; b3s += ccB * vB.z; b4s += ccB * vB.w;
                }
            }
        } else {
            for (; k < e; k += 8) {
                const float ccA = coeff[k];
                const float4 vA = *reinterpret_cast<const float4*>(ea + node[k] * 4);
                a0 += ccA; a1 += ccA * vA.x; a2 += ccA * vA.y; a3 += ccA * vA.z; a4 += ccA * vA.w;
                if (k + 1 < e) {
                    const float ccB = coeff[k + 1];
                    const float4 vB = *reinterpret_cast<const float4*>(ea + node[k + 1] * 4);
                    b0s += ccB; b1s += ccB * vB.x; b2s += ccB * vB.y; b3s += ccB * vB.z; b4s += ccB * vB.w;
                }
            }
        }
    }
    a0 += b0s; a1 += b1s; a2 += b2s; a3 += b3s; a4 += b4s;
#pragma unroll
    for (int d = 1; d < 4; d <<= 1) {
        a0 += __shfl_xor(a0, d); a1 += __shfl_xor(a1, d); a2 += __shfl_xor(a2, d);
        a3 += __shfl_xor(a3, d); a4 += __shfl_xor(a4, d);
    }
    if (sub == 0) {
        sum[0][q] = a0; sum[1][q] = a1; sum[2][q] = a2;
        sum[3][q] = a3; sum[4][q] = a4;
    }
    __syncthreads();

    // expansion: wave w, lane l; group g = l&15 -> pairs 4g..4g+3;
    // channels h = w*8 + (l>>4)*2 + j, j in {0,1}.
    {
        const int l = t & 63, w = t >> 6;
        const int g = l & 15, quad = l >> 4;
        const v4f c0 = *reinterpret_cast<const v4f*>(&sum[0][4 * g]);
        const v4f c1 = *reinterpret_cast<const v4f*>(&sum[1][4 * g]);
        const v4f c2 = *reinterpret_cast<const v4f*>(&sum[2][4 * g]);
        const v4f c3 = *reinterpret_cast<const v4f*>(&sum[3][4 * g]);
        const v4f c4 = *reinterpret_cast<const v4f*>(&sum[4][4 * g]);
        const size_t op = (size_t)p0 + 4 * g;
#pragma unroll
        for (int j = 0; j < 2; ++j) {
            const int h = w * 8 + quad * 2 + j;
            const float bb = sBias[h], w0 = sW[h * 4], w1 = sW[h * 4 + 1],
                        w2 = sW[h * 4 + 2], w3 = sW[h * 4 + 3];
            v4f o = bb * c0 + w0 * c1 + w1 * c2 + w2 * c3 + w3 * c4;
            __builtin_nontemporal_store(o, reinterpret_cast<v4f*>(out + (size_t)h * N2 + op));
        }
    }
}

extern "C" void kernel_launch(void* const* d_in, const int* in_sizes, int n_in,
                              void* d_out, int out_size, void* d_ws, size_t ws_size,
                              hipStream_t stream) {
    // inputs: 0=x 1=edge_attr 2=W 3=b 4=edge_idx 5=pair_idx 6=node_idx 7=coeff 8=num_nodes
    const float* ea    = (const float*)d_in[1];
    const float* W     = (const float*)d_in[2];
    const float* b     = (const float*)d_in[3];
    const int*   pair  = (const int*)d_in[5];
    const int*   node  = (const int*)d_in[6];
    const float* coeff = (const float*)d_in[7];
    float* out = (float*)d_out;
    int M = in_sizes[5];

    int* bnd = (int*)d_ws;   // N2/PPB + 1 = 9217 ints

    bounds_kernel<<<(N2 / PPB + 1 + 255) / 256, 256, 0, stream>>>(pair, coeff, bnd, M);

    fused_kernel<<<N2 / PPB, TPB, 0, stream>>>(pair, node, coeff, ea, W, b, bnd, out, M);
}